// Round 9
// baseline (204.403 us; speedup 1.0000x reference)
//
#include <hip/hip_runtime.h>
#include <hip/hip_bf16.h>
#include <stdint.h>

// Segment = 4096 contiguous floats (16 KB) of one polynomial row.
// Degrees 8,7,6,5,4 -> counts 8*4096, 8*512, 8*64, 8*8, 8*1 = 37448 segments.
// Work quantum = quarter-segment (4 chunks x 1KB = 4KB), NQ = NSEG*4.
#define OFF7 32768
#define OFF6 36864
#define OFF5 37376
#define OFF4 37440
#define NSEG 37448
#define NQ   (NSEG * 4)

typedef __attribute__((address_space(1))) const uint32_t g_u32;
typedef __attribute__((address_space(3))) uint32_t l_u32;

// async HBM->LDS DMA, 16B per lane; LDS dest = wave-uniform base + lane*16.
__device__ __forceinline__ void gload_lds16(const float* g, float* l) {
    __builtin_amdgcn_global_load_lds((g_u32*)g, (l_u32*)l, 16, 0, 0);
}

__device__ __forceinline__ float4 mul4(float4 a, float4 b) {
    return make_float4(a.x * b.x, a.y * b.y, a.z * b.z, a.w * b.w);
}
__device__ __forceinline__ float4 fma4s(float s, float4 b, float4 c) {
    return make_float4(fmaf(s, b.x, c.x), fmaf(s, b.y, c.y),
                       fmaf(s, b.z, c.z), fmaf(s, b.w, c.w));
}
__device__ __forceinline__ float4 fma44(float4 a, float4 b, float4 c) {
    return make_float4(fmaf(a.x, b.x, c.x), fmaf(a.y, b.y, c.y),
                       fmaf(a.z, b.z, c.z), fmaf(a.w, b.w, c.w));
}

struct SegInfo {
    const float* seg;  // segment base (4096 floats)
    float4 th;         // per-segment high Kronecker factor (4 neurons)
    int p;             // polynomial row 0..7
};

__device__ __forceinline__ SegInfo seg_decode(
    int g,
    const float* c4, const float* c5, const float* c6,
    const float* c7, const float* c8,
    const float4* T1s, const float4* T2s)
{
    SegInfo si;
    if (g < OFF7) {
        si.p = g >> 12; int hi = g & 4095;
        si.seg = c8 + ((size_t)si.p << 24) + ((size_t)hi << 12);
        si.th = mul4(T2s[hi >> 6], T2s[hi & 63]);
    } else if (g < OFF6) {
        int t = g - OFF7; si.p = t >> 9; int hi = t & 511;
        si.seg = c7 + ((size_t)si.p << 21) + ((size_t)hi << 12);
        si.th = mul4(T1s[hi >> 6], T2s[hi & 63]);
    } else if (g < OFF5) {
        int t = g - OFF6; si.p = t >> 6; int hi = t & 63;
        si.seg = c6 + ((size_t)si.p << 18) + ((size_t)hi << 12);
        si.th = T2s[hi];
    } else if (g < OFF4) {
        int t = g - OFF5; si.p = t >> 3; int hi = t & 7;
        si.seg = c5 + ((size_t)si.p << 15) + ((size_t)hi << 12);
        si.th = T1s[hi];
    } else {
        si.p = g - OFF4;
        si.seg = c4 + ((size_t)si.p << 12);
        si.th = make_float4(1.f, 1.f, 1.f, 1.f);
    }
    return si;
}

// Stage quantum (segment seg, quarter u) into this wave's private LDS half:
// chunk j (1KB) -> dst + j*256 floats. vmcnt += 4 per call.
#define STAGE(dst, segptr, u) { \
    _Pragma("unroll") \
    for (int j_ = 0; j_ < 4; ++j_) { \
        gload_lds16((segptr) + ((((u) << 2) + j_) << 8) + (lane << 2), \
                    (dst) + (j_ << 8)); \
    } }

// Barrier-free wave-private pipeline over degrees 4..8 (round-7 streaming:
// each global wave owns a CONTIGUOUS quantum range -> 4096 sequential DRAM
// streams; r8 proved interleaving waves regresses since they drift without
// barriers). Loop: STAGE next quantum into other half, s_waitcnt vmcnt(4)
// (previous landed, next stays in flight), compute own half. No
// __syncthreads in the loop; flush = device atomicAdd into out[32]
// (out freshly initialized each call by poly_small: bias + degrees 1..3).
// Identity per element m = c*256 + lane*4 + j of a segment (c = 4u+q):
// kron^4[m] = T2[c*4 + lane/16] * T2[(lane&15)*4 + j].
__global__ __launch_bounds__(256) void poly_big(
    const float* __restrict__ X,
    const float* __restrict__ c4, const float* __restrict__ c5,
    const float* __restrict__ c6, const float* __restrict__ c7,
    const float* __restrict__ c8, float* __restrict__ out)
{
    __shared__ float4 T1s[8], T2s[64];
    __shared__ float buf[2][4096];
    const int tid = threadIdx.x;

    if (tid < 8)  T1s[tid] = make_float4(X[tid], X[8 + tid], X[16 + tid], X[24 + tid]);
    __syncthreads();
    if (tid < 64) T2s[tid] = mul4(T1s[tid >> 3], T1s[tid & 7]);
    __syncthreads();

    const int wave = tid >> 6;
    const int lane = tid & 63;
    const int lhi  = lane >> 4;
    const float4 tl0 = T2s[((lane & 15) << 2) + 0];
    const float4 tl1 = T2s[((lane & 15) << 2) + 1];
    const float4 tl2 = T2s[((lane & 15) << 2) + 2];
    const float4 tl3 = T2s[((lane & 15) << 2) + 3];

    const int wg = (blockIdx.x << 2) + wave;     // global wave id
    const int NW = gridDim.x << 2;
    int Q    = (int)(((long long)wg * NQ) / NW);
    int Qend = (int)(((long long)(wg + 1) * NQ) / NW);

    if (Q < Qend) {
        float* cbuf = &buf[0][wave << 10];
        float* nbuf = &buf[1][wave << 10];

        SegInfo cur = seg_decode(Q >> 2, c4, c5, c6, c7, c8, T1s, T2s);
        int curu = Q & 3;
        int curp = cur.p;
        STAGE(cbuf, cur.seg, curu);

        float4 runacc = make_float4(0.f, 0.f, 0.f, 0.f);
        for (;;) {
            const bool more = (Q + 1) < Qend;
            SegInfo nxt = cur;
            int nxtu = curu;
            if (more) {
                nxtu = (Q + 1) & 3;
                nxt = seg_decode((Q + 1) >> 2, c4, c5, c6, c7, c8, T1s, T2s);
                STAGE(nbuf, nxt.seg, nxtu);
                asm volatile("s_waitcnt vmcnt(4)" ::: "memory");
            } else {
                asm volatile("s_waitcnt vmcnt(0)" ::: "memory");
            }

            float4 acc = make_float4(0.f, 0.f, 0.f, 0.f);
            #pragma unroll
            for (int q = 0; q < 4; ++q) {
                const float4 cv = *(const float4*)&cbuf[(q << 8) + (lane << 2)];
                const float4 th = T2s[(curu << 4) + (q << 2) + lhi];
                float4 inner = make_float4(cv.x * tl0.x, cv.x * tl0.y,
                                           cv.x * tl0.z, cv.x * tl0.w);
                inner = fma4s(cv.y, tl1, inner);
                inner = fma4s(cv.z, tl2, inner);
                inner = fma4s(cv.w, tl3, inner);
                acc = fma44(th, inner, acc);
            }
            runacc = fma44(acc, cur.th, runacc);

            if (!more || nxt.p != curp) {   // wave-uniform, rare
                float vx = runacc.x, vy = runacc.y, vz = runacc.z, vw = runacc.w;
                #pragma unroll
                for (int m = 32; m; m >>= 1) {
                    vx += __shfl_xor(vx, m);
                    vy += __shfl_xor(vy, m);
                    vz += __shfl_xor(vz, m);
                    vw += __shfl_xor(vw, m);
                }
                if (lane == 0) {
                    atomicAdd(&out[ 0 + curp], vx);
                    atomicAdd(&out[ 8 + curp], vy);
                    atomicAdd(&out[16 + curp], vz);
                    atomicAdd(&out[24 + curp], vw);
                }
                runacc = make_float4(0.f, 0.f, 0.f, 0.f);
                curp = nxt.p;
            }
            if (!more) break;
            float* t_ = cbuf; cbuf = nbuf; nbuf = t_;
            cur = nxt; curu = nxtu; ++Q;
        }
    }
}

// Runs FIRST each call: out[neu*8+p] = bias[p] + degrees 1..3 (fresh write,
// so graph replays stay deterministic despite poly_big's atomics).
__global__ __launch_bounds__(256) void poly_small(
    const float* __restrict__ X, const float* __restrict__ bias,
    const float* __restrict__ c1, const float* __restrict__ c2,
    const float* __restrict__ c3, float* __restrict__ out)
{
    __shared__ float xs[4][8];
    const int t = threadIdx.x;
    if (t < 32) xs[t >> 3][t & 7] = X[t];
    __syncthreads();

    const int p = t >> 5, li = t & 31;
    float s0 = 0.f, s1 = 0.f, s2 = 0.f, s3 = 0.f;
    for (int i = li; i < 512; i += 32) {
        float cv = c3[(p << 9) + i];
        int d1 = (i >> 6) & 7, d2 = (i >> 3) & 7, d3 = i & 7;
        s0 = fmaf(cv, xs[0][d1] * xs[0][d2] * xs[0][d3], s0);
        s1 = fmaf(cv, xs[1][d1] * xs[1][d2] * xs[1][d3], s1);
        s2 = fmaf(cv, xs[2][d1] * xs[2][d2] * xs[2][d3], s2);
        s3 = fmaf(cv, xs[3][d1] * xs[3][d2] * xs[3][d3], s3);
    }
    for (int i = li; i < 64; i += 32) {
        float cv = c2[(p << 6) + i];
        int d1 = (i >> 3) & 7, d2 = i & 7;
        s0 = fmaf(cv, xs[0][d1] * xs[0][d2], s0);
        s1 = fmaf(cv, xs[1][d1] * xs[1][d2], s1);
        s2 = fmaf(cv, xs[2][d1] * xs[2][d2], s2);
        s3 = fmaf(cv, xs[3][d1] * xs[3][d2], s3);
    }
    if (li < 8) {
        float cv = c1[(p << 3) + li];
        s0 = fmaf(cv, xs[0][li], s0);
        s1 = fmaf(cv, xs[1][li], s1);
        s2 = fmaf(cv, xs[2][li], s2);
        s3 = fmaf(cv, xs[3][li], s3);
    }
    // reduce within each 32-lane polynomial group (masks < 32 stay in-group)
    #pragma unroll
    for (int m = 16; m; m >>= 1) {
        s0 += __shfl_xor(s0, m);
        s1 += __shfl_xor(s1, m);
        s2 += __shfl_xor(s2, m);
        s3 += __shfl_xor(s3, m);
    }
    if (li == 0) {
        const float b = bias[p];
        out[ 0 + p] = b + s0;
        out[ 8 + p] = b + s1;
        out[16 + p] = b + s2;
        out[24 + p] = b + s3;
    }
}

extern "C" void kernel_launch(void* const* d_in, const int* in_sizes, int n_in,
                              void* d_out, int out_size, void* d_ws, size_t ws_size,
                              hipStream_t stream) {
    const float* X    = (const float*)d_in[0];
    const float* bias = (const float*)d_in[1];
    const float* c1   = (const float*)d_in[2];
    const float* c2   = (const float*)d_in[3];
    const float* c3   = (const float*)d_in[4];
    const float* c4   = (const float*)d_in[5];
    const float* c5   = (const float*)d_in[6];
    const float* c6   = (const float*)d_in[7];
    const float* c7   = (const float*)d_in[8];
    const float* c8   = (const float*)d_in[9];
    float* out = (float*)d_out;

    // poly_small initializes out (bias + deg1-3); poly_big atomically
    // accumulates deg4-8 on top (same stream -> ordered).
    poly_small<<<1, 256, 0, stream>>>(X, bias, c1, c2, c3, out);
    // exactly 4 blocks/CU x 256 CUs resident (LDS-capped): no dispatch tail.
    poly_big<<<1024, 256, 0, stream>>>(X, c4, c5, c6, c7, c8, out);
}

// Round 10
// 131.441 us; speedup vs baseline: 1.5551x; 1.5551x over previous
//
#include <hip/hip_runtime.h>
#include <hip/hip_bf16.h>
#include <stdint.h>

// Segment = 4096 contiguous floats (16 KB) of one polynomial row.
// Degrees 8,7,6,5,4 -> counts 8*4096, 8*512, 8*64, 8*8, 8*1 = 37448 segments.
// Work quantum = quarter-segment (4 chunks x 1KB = 4KB), NQ = NSEG*4.
#define OFF7 32768
#define OFF6 36864
#define OFF5 37376
#define OFF4 37440
#define NSEG 37448
#define NQ   (NSEG * 4)

typedef __attribute__((address_space(1))) const uint32_t g_u32;
typedef __attribute__((address_space(3))) uint32_t l_u32;

// async HBM->LDS DMA, 16B per lane; LDS dest = wave-uniform base + lane*16.
__device__ __forceinline__ void gload_lds16(const float* g, float* l) {
    __builtin_amdgcn_global_load_lds((g_u32*)g, (l_u32*)l, 16, 0, 0);
}

__device__ __forceinline__ float4 mul4(float4 a, float4 b) {
    return make_float4(a.x * b.x, a.y * b.y, a.z * b.z, a.w * b.w);
}
__device__ __forceinline__ float4 fma4s(float s, float4 b, float4 c) {
    return make_float4(fmaf(s, b.x, c.x), fmaf(s, b.y, c.y),
                       fmaf(s, b.z, c.z), fmaf(s, b.w, c.w));
}
__device__ __forceinline__ float4 fma44(float4 a, float4 b, float4 c) {
    return make_float4(fmaf(a.x, b.x, c.x), fmaf(a.y, b.y, c.y),
                       fmaf(a.z, b.z, c.z), fmaf(a.w, b.w, c.w));
}

struct SegInfo {
    const float* seg;  // segment base (4096 floats)
    float4 th;         // per-segment high Kronecker factor (4 neurons)
    int p;             // polynomial row 0..7
};

__device__ __forceinline__ SegInfo seg_decode(
    int g,
    const float* c4, const float* c5, const float* c6,
    const float* c7, const float* c8,
    const float4* T1s, const float4* T2s)
{
    SegInfo si;
    if (g < OFF7) {
        si.p = g >> 12; int hi = g & 4095;
        si.seg = c8 + ((size_t)si.p << 24) + ((size_t)hi << 12);
        si.th = mul4(T2s[hi >> 6], T2s[hi & 63]);
    } else if (g < OFF6) {
        int t = g - OFF7; si.p = t >> 9; int hi = t & 511;
        si.seg = c7 + ((size_t)si.p << 21) + ((size_t)hi << 12);
        si.th = mul4(T1s[hi >> 6], T2s[hi & 63]);
    } else if (g < OFF5) {
        int t = g - OFF6; si.p = t >> 6; int hi = t & 63;
        si.seg = c6 + ((size_t)si.p << 18) + ((size_t)hi << 12);
        si.th = T2s[hi];
    } else if (g < OFF4) {
        int t = g - OFF5; si.p = t >> 3; int hi = t & 7;
        si.seg = c5 + ((size_t)si.p << 15) + ((size_t)hi << 12);
        si.th = T1s[hi];
    } else {
        si.p = g - OFF4;
        si.seg = c4 + ((size_t)si.p << 12);
        si.th = make_float4(1.f, 1.f, 1.f, 1.f);
    }
    return si;
}

// Stage quantum (segment seg, quarter u) into this wave's private LDS half:
// chunk j (1KB) -> dst + j*256 floats. vmcnt += 4 per call.
#define STAGE(dst, segptr, u) { \
    _Pragma("unroll") \
    for (int j_ = 0; j_ < 4; ++j_) { \
        gload_lds16((segptr) + ((((u) << 2) + j_) << 8) + (lane << 2), \
                    (dst) + (j_ << 8)); \
    } }

// Barrier-free wave-private pipeline over degrees 4..8 (proven r7 structure:
// each global wave owns a CONTIGUOUS quantum range -> 4096 sequential DRAM
// streams). Loop: STAGE next quantum into other half, s_waitcnt vmcnt(4)
// (previous landed, next stays in flight), compute own half. No
// __syncthreads in the loop. Flush = LDS atomics into part[32] (rare);
// block writes 32 non-atomic partials to ws (kernel boundary is the sync —
// r8/r9 proved same-line global atomics cost ~70us serialized).
// Identity per element m = c*256 + lane*4 + j of a segment (c = 4u+q):
// kron^4[m] = T2[c*4 + lane/16] * T2[(lane&15)*4 + j].
__global__ __launch_bounds__(256) void poly_big(
    const float* __restrict__ X,
    const float* __restrict__ c4, const float* __restrict__ c5,
    const float* __restrict__ c6, const float* __restrict__ c7,
    const float* __restrict__ c8, float* __restrict__ ws)
{
    __shared__ float4 T1s[8], T2s[64];
    __shared__ float part[32];
    __shared__ float buf[2][4096];
    const int tid = threadIdx.x;

    if (tid < 8)  T1s[tid] = make_float4(X[tid], X[8 + tid], X[16 + tid], X[24 + tid]);
    if (tid < 32) part[tid] = 0.f;
    __syncthreads();
    if (tid < 64) T2s[tid] = mul4(T1s[tid >> 3], T1s[tid & 7]);
    __syncthreads();

    const int wave = tid >> 6;
    const int lane = tid & 63;
    const int lhi  = lane >> 4;
    const float4 tl0 = T2s[((lane & 15) << 2) + 0];
    const float4 tl1 = T2s[((lane & 15) << 2) + 1];
    const float4 tl2 = T2s[((lane & 15) << 2) + 2];
    const float4 tl3 = T2s[((lane & 15) << 2) + 3];

    const int wg = (blockIdx.x << 2) + wave;     // global wave id
    const int NW = gridDim.x << 2;
    int Q    = (int)(((long long)wg * NQ) / NW);
    int Qend = (int)(((long long)(wg + 1) * NQ) / NW);

    if (Q < Qend) {
        float* cbuf = &buf[0][wave << 10];
        float* nbuf = &buf[1][wave << 10];

        SegInfo cur = seg_decode(Q >> 2, c4, c5, c6, c7, c8, T1s, T2s);
        int curu = Q & 3;
        int curp = cur.p;
        STAGE(cbuf, cur.seg, curu);

        float4 runacc = make_float4(0.f, 0.f, 0.f, 0.f);
        for (;;) {
            const bool more = (Q + 1) < Qend;
            SegInfo nxt = cur;
            int nxtu = curu;
            if (more) {
                nxtu = (Q + 1) & 3;
                nxt = seg_decode((Q + 1) >> 2, c4, c5, c6, c7, c8, T1s, T2s);
                STAGE(nbuf, nxt.seg, nxtu);
                asm volatile("s_waitcnt vmcnt(4)" ::: "memory");
            } else {
                asm volatile("s_waitcnt vmcnt(0)" ::: "memory");
            }

            float4 acc = make_float4(0.f, 0.f, 0.f, 0.f);
            #pragma unroll
            for (int q = 0; q < 4; ++q) {
                const float4 cv = *(const float4*)&cbuf[(q << 8) + (lane << 2)];
                const float4 th = T2s[(curu << 4) + (q << 2) + lhi];
                float4 inner = make_float4(cv.x * tl0.x, cv.x * tl0.y,
                                           cv.x * tl0.z, cv.x * tl0.w);
                inner = fma4s(cv.y, tl1, inner);
                inner = fma4s(cv.z, tl2, inner);
                inner = fma4s(cv.w, tl3, inner);
                acc = fma44(th, inner, acc);
            }
            runacc = fma44(acc, cur.th, runacc);

            if (!more || nxt.p != curp) {   // wave-uniform, rare
                float vx = runacc.x, vy = runacc.y, vz = runacc.z, vw = runacc.w;
                #pragma unroll
                for (int m = 32; m; m >>= 1) {
                    vx += __shfl_xor(vx, m);
                    vy += __shfl_xor(vy, m);
                    vz += __shfl_xor(vz, m);
                    vw += __shfl_xor(vw, m);
                }
                if (lane == 0) {
                    atomicAdd(&part[(curp << 2) + 0], vx);
                    atomicAdd(&part[(curp << 2) + 1], vy);
                    atomicAdd(&part[(curp << 2) + 2], vz);
                    atomicAdd(&part[(curp << 2) + 3], vw);
                }
                runacc = make_float4(0.f, 0.f, 0.f, 0.f);
                curp = nxt.p;
            }
            if (!more) break;
            float* t_ = cbuf; cbuf = nbuf; nbuf = t_;
            cur = nxt; curu = nxtu; ++Q;
        }
    }
    __syncthreads();
    // ws layout: [o][block] with o = neu*8 + p  (transposed for coalesced
    // poly_final reads). part is stored as (p<<2)+neu -> remap.
    if (tid < 32)
        ws[(size_t)tid * gridDim.x + blockIdx.x] = part[((tid & 7) << 2) + (tid >> 3)];
}

// Finalize: reduce block partials (1024 threads wide) + bias + degrees 1..3.
__global__ __launch_bounds__(1024) void poly_final(
    const float* __restrict__ X, const float* __restrict__ bias,
    const float* __restrict__ c1, const float* __restrict__ c2,
    const float* __restrict__ c3, const float* __restrict__ ws,
    int nblocks, float* __restrict__ out)
{
    __shared__ float xs[4][8];
    __shared__ float redA[32][32];   // [o][grp]
    __shared__ float redB[8][32][4];
    const int t = threadIdx.x;
    if (t < 32) xs[t >> 3][t & 7] = X[t];
    __syncthreads();

    // Phase A: sum big-kernel partials. ws is [o][block]; 32 lanes of a
    // group read consecutive blocks -> coalesced.
    {
        int o = t >> 5, grp = t & 31;
        float s = 0.f;
        for (int b = grp; b < nblocks; b += 32) s += ws[(size_t)o * nblocks + b];
        redA[o][grp] = s;
    }
    // Phase B: degrees 1..3 on threads 0..255. p = t>>5, 32 lanes per poly.
    if (t < 256) {
        int p = t >> 5, li = t & 31;
        float s0 = 0.f, s1 = 0.f, s2 = 0.f, s3 = 0.f;
        for (int i = li; i < 512; i += 32) {
            float cv = c3[(p << 9) + i];
            int d1 = (i >> 6) & 7, d2 = (i >> 3) & 7, d3 = i & 7;
            s0 = fmaf(cv, xs[0][d1] * xs[0][d2] * xs[0][d3], s0);
            s1 = fmaf(cv, xs[1][d1] * xs[1][d2] * xs[1][d3], s1);
            s2 = fmaf(cv, xs[2][d1] * xs[2][d2] * xs[2][d3], s2);
            s3 = fmaf(cv, xs[3][d1] * xs[3][d2] * xs[3][d3], s3);
        }
        for (int i = li; i < 64; i += 32) {
            float cv = c2[(p << 6) + i];
            int d1 = (i >> 3) & 7, d2 = i & 7;
            s0 = fmaf(cv, xs[0][d1] * xs[0][d2], s0);
            s1 = fmaf(cv, xs[1][d1] * xs[1][d2], s1);
            s2 = fmaf(cv, xs[2][d1] * xs[2][d2], s2);
            s3 = fmaf(cv, xs[3][d1] * xs[3][d2], s3);
        }
        if (li < 8) {
            float cv = c1[(p << 3) + li];
            s0 = fmaf(cv, xs[0][li], s0);
            s1 = fmaf(cv, xs[1][li], s1);
            s2 = fmaf(cv, xs[2][li], s2);
            s3 = fmaf(cv, xs[3][li], s3);
        }
        redB[p][li][0] = s0; redB[p][li][1] = s1; redB[p][li][2] = s2; redB[p][li][3] = s3;
    }
    __syncthreads();
    if (t < 32) {
        int neu = t >> 3, p = t & 7;
        float tot = bias[p];
        #pragma unroll
        for (int grp = 0; grp < 32; ++grp) tot += redA[t][grp];
        for (int li = 0; li < 32; ++li) tot += redB[p][li][neu];
        out[t] = tot;
    }
}

extern "C" void kernel_launch(void* const* d_in, const int* in_sizes, int n_in,
                              void* d_out, int out_size, void* d_ws, size_t ws_size,
                              hipStream_t stream) {
    const float* X    = (const float*)d_in[0];
    const float* bias = (const float*)d_in[1];
    const float* c1   = (const float*)d_in[2];
    const float* c2   = (const float*)d_in[3];
    const float* c3   = (const float*)d_in[4];
    const float* c4   = (const float*)d_in[5];
    const float* c5   = (const float*)d_in[6];
    const float* c6   = (const float*)d_in[7];
    const float* c7   = (const float*)d_in[8];
    const float* c8   = (const float*)d_in[9];
    float* out = (float*)d_out;
    float* ws  = (float*)d_ws;

    // exactly 4 blocks/CU x 256 CUs resident (LDS-capped): no dispatch tail.
    int blocks = 1024;
    size_t maxb = ws_size / (32 * sizeof(float));
    if ((size_t)blocks > maxb) blocks = (int)maxb;
    if (blocks < 1) blocks = 1;

    poly_big<<<blocks, 256, 0, stream>>>(X, c4, c5, c6, c7, c8, ws);
    poly_final<<<1, 1024, 0, stream>>>(X, bias, c1, c2, c3, ws, blocks, out);
}

// Round 11
// 110.050 us; speedup vs baseline: 1.8574x; 1.1944x over previous
//
#include <hip/hip_runtime.h>
#include <hip/hip_bf16.h>
#include <stdint.h>

// Segment = 4096 contiguous floats (16 KB) of one polynomial row.
// Degrees 8,7,6,5,4 -> counts 8*4096, 8*512, 8*64, 8*8, 8*1 = 37448 segments.
// Work quantum = quarter-segment (4 chunks x 1KB = 4KB), NQ = NSEG*4.
#define OFF7 32768
#define OFF6 36864
#define OFF5 37376
#define OFF4 37440
#define NSEG 37448
#define NQ   (NSEG * 4)

typedef __attribute__((address_space(1))) const uint32_t g_u32;
typedef __attribute__((address_space(3))) uint32_t l_u32;

// async HBM->LDS DMA, 16B per lane; LDS dest = wave-uniform base + lane*16.
// aux=2 = NT (non-temporal) CPol bit on gfx94x/gfx950: streaming read, do
// not allocate in L2/LLC (613 MB/call would otherwise thrash the 256 MB LLC).
__device__ __forceinline__ void gload_lds16(const float* g, float* l) {
    __builtin_amdgcn_global_load_lds((g_u32*)g, (l_u32*)l, 16, 0, 2);
}

__device__ __forceinline__ float4 mul4(float4 a, float4 b) {
    return make_float4(a.x * b.x, a.y * b.y, a.z * b.z, a.w * b.w);
}
__device__ __forceinline__ float4 fma4s(float s, float4 b, float4 c) {
    return make_float4(fmaf(s, b.x, c.x), fmaf(s, b.y, c.y),
                       fmaf(s, b.z, c.z), fmaf(s, b.w, c.w));
}
__device__ __forceinline__ float4 fma44(float4 a, float4 b, float4 c) {
    return make_float4(fmaf(a.x, b.x, c.x), fmaf(a.y, b.y, c.y),
                       fmaf(a.z, b.z, c.z), fmaf(a.w, b.w, c.w));
}

struct SegInfo {
    const float* seg;  // segment base (4096 floats)
    float4 th;         // per-segment high Kronecker factor (4 neurons)
    int p;             // polynomial row 0..7
};

__device__ __forceinline__ SegInfo seg_decode(
    int g,
    const float* c4, const float* c5, const float* c6,
    const float* c7, const float* c8,
    const float4* T1s, const float4* T2s)
{
    SegInfo si;
    if (g < OFF7) {
        si.p = g >> 12; int hi = g & 4095;
        si.seg = c8 + ((size_t)si.p << 24) + ((size_t)hi << 12);
        si.th = mul4(T2s[hi >> 6], T2s[hi & 63]);
    } else if (g < OFF6) {
        int t = g - OFF7; si.p = t >> 9; int hi = t & 511;
        si.seg = c7 + ((size_t)si.p << 21) + ((size_t)hi << 12);
        si.th = mul4(T1s[hi >> 6], T2s[hi & 63]);
    } else if (g < OFF5) {
        int t = g - OFF6; si.p = t >> 6; int hi = t & 63;
        si.seg = c6 + ((size_t)si.p << 18) + ((size_t)hi << 12);
        si.th = T2s[hi];
    } else if (g < OFF4) {
        int t = g - OFF5; si.p = t >> 3; int hi = t & 7;
        si.seg = c5 + ((size_t)si.p << 15) + ((size_t)hi << 12);
        si.th = T1s[hi];
    } else {
        si.p = g - OFF4;
        si.seg = c4 + ((size_t)si.p << 12);
        si.th = make_float4(1.f, 1.f, 1.f, 1.f);
    }
    return si;
}

// Stage quantum (segment seg, quarter u) into this wave's private LDS half:
// chunk j (1KB) -> dst + j*256 floats. vmcnt += 4 per call.
#define STAGE(dst, segptr, u) { \
    _Pragma("unroll") \
    for (int j_ = 0; j_ < 4; ++j_) { \
        gload_lds16((segptr) + ((((u) << 2) + j_) << 8) + (lane << 2), \
                    (dst) + (j_ << 8)); \
    } }

// Barrier-free wave-private pipeline over degrees 4..8 (proven r7/r10
// structure: each global wave owns a CONTIGUOUS quantum range -> 4096
// sequential DRAM streams). Loop: STAGE next quantum into other half,
// s_waitcnt vmcnt(4) (previous landed, next stays in flight), compute own
// half. No __syncthreads in the loop. Flush = LDS atomics into part[32]
// (rare); block writes 32 non-atomic partials to ws (kernel boundary is
// the sync — r8/r9 proved same-line global atomics cost ~70us serialized).
// Identity per element m = c*256 + lane*4 + j of a segment (c = 4u+q):
// kron^4[m] = T2[c*4 + lane/16] * T2[(lane&15)*4 + j].
__global__ __launch_bounds__(256) void poly_big(
    const float* __restrict__ X,
    const float* __restrict__ c4, const float* __restrict__ c5,
    const float* __restrict__ c6, const float* __restrict__ c7,
    const float* __restrict__ c8, float* __restrict__ ws)
{
    __shared__ float4 T1s[8], T2s[64];
    __shared__ float part[32];
    __shared__ float buf[2][4096];
    const int tid = threadIdx.x;

    if (tid < 8)  T1s[tid] = make_float4(X[tid], X[8 + tid], X[16 + tid], X[24 + tid]);
    if (tid < 32) part[tid] = 0.f;
    __syncthreads();
    if (tid < 64) T2s[tid] = mul4(T1s[tid >> 3], T1s[tid & 7]);
    __syncthreads();

    const int wave = tid >> 6;
    const int lane = tid & 63;
    const int lhi  = lane >> 4;
    const float4 tl0 = T2s[((lane & 15) << 2) + 0];
    const float4 tl1 = T2s[((lane & 15) << 2) + 1];
    const float4 tl2 = T2s[((lane & 15) << 2) + 2];
    const float4 tl3 = T2s[((lane & 15) << 2) + 3];

    const int wg = (blockIdx.x << 2) + wave;     // global wave id
    const int NW = gridDim.x << 2;
    int Q    = (int)(((long long)wg * NQ) / NW);
    int Qend = (int)(((long long)(wg + 1) * NQ) / NW);

    if (Q < Qend) {
        float* cbuf = &buf[0][wave << 10];
        float* nbuf = &buf[1][wave << 10];

        SegInfo cur = seg_decode(Q >> 2, c4, c5, c6, c7, c8, T1s, T2s);
        int curu = Q & 3;
        int curp = cur.p;
        STAGE(cbuf, cur.seg, curu);

        float4 runacc = make_float4(0.f, 0.f, 0.f, 0.f);
        for (;;) {
            const bool more = (Q + 1) < Qend;
            SegInfo nxt = cur;
            int nxtu = curu;
            if (more) {
                nxtu = (Q + 1) & 3;
                nxt = seg_decode((Q + 1) >> 2, c4, c5, c6, c7, c8, T1s, T2s);
                STAGE(nbuf, nxt.seg, nxtu);
                asm volatile("s_waitcnt vmcnt(4)" ::: "memory");
            } else {
                asm volatile("s_waitcnt vmcnt(0)" ::: "memory");
            }

            float4 acc = make_float4(0.f, 0.f, 0.f, 0.f);
            #pragma unroll
            for (int q = 0; q < 4; ++q) {
                const float4 cv = *(const float4*)&cbuf[(q << 8) + (lane << 2)];
                const float4 th = T2s[(curu << 4) + (q << 2) + lhi];
                float4 inner = make_float4(cv.x * tl0.x, cv.x * tl0.y,
                                           cv.x * tl0.z, cv.x * tl0.w);
                inner = fma4s(cv.y, tl1, inner);
                inner = fma4s(cv.z, tl2, inner);
                inner = fma4s(cv.w, tl3, inner);
                acc = fma44(th, inner, acc);
            }
            runacc = fma44(acc, cur.th, runacc);

            if (!more || nxt.p != curp) {   // wave-uniform, rare
                float vx = runacc.x, vy = runacc.y, vz = runacc.z, vw = runacc.w;
                #pragma unroll
                for (int m = 32; m; m >>= 1) {
                    vx += __shfl_xor(vx, m);
                    vy += __shfl_xor(vy, m);
                    vz += __shfl_xor(vz, m);
                    vw += __shfl_xor(vw, m);
                }
                if (lane == 0) {
                    atomicAdd(&part[(curp << 2) + 0], vx);
                    atomicAdd(&part[(curp << 2) + 1], vy);
                    atomicAdd(&part[(curp << 2) + 2], vz);
                    atomicAdd(&part[(curp << 2) + 3], vw);
                }
                runacc = make_float4(0.f, 0.f, 0.f, 0.f);
                curp = nxt.p;
            }
            if (!more) break;
            float* t_ = cbuf; cbuf = nbuf; nbuf = t_;
            cur = nxt; curu = nxtu; ++Q;
        }
    }
    __syncthreads();
    // ws layout: [o][block] with o = neu*8 + p  (transposed for coalesced
    // poly_final reads). part is stored as (p<<2)+neu -> remap.
    if (tid < 32)
        ws[(size_t)tid * gridDim.x + blockIdx.x] = part[((tid & 7) << 2) + (tid >> 3)];
}

// Finalize: reduce block partials (1024 threads wide) + bias + degrees 1..3.
__global__ __launch_bounds__(1024) void poly_final(
    const float* __restrict__ X, const float* __restrict__ bias,
    const float* __restrict__ c1, const float* __restrict__ c2,
    const float* __restrict__ c3, const float* __restrict__ ws,
    int nblocks, float* __restrict__ out)
{
    __shared__ float xs[4][8];
    __shared__ float redA[32][32];   // [o][grp]
    __shared__ float redB[8][32][4];
    const int t = threadIdx.x;
    if (t < 32) xs[t >> 3][t & 7] = X[t];
    __syncthreads();

    // Phase A: sum big-kernel partials. ws is [o][block]; 32 lanes of a
    // group read consecutive blocks -> coalesced.
    {
        int o = t >> 5, grp = t & 31;
        float s = 0.f;
        for (int b = grp; b < nblocks; b += 32) s += ws[(size_t)o * nblocks + b];
        redA[o][grp] = s;
    }
    // Phase B: degrees 1..3 on threads 0..255. p = t>>5, 32 lanes per poly.
    if (t < 256) {
        int p = t >> 5, li = t & 31;
        float s0 = 0.f, s1 = 0.f, s2 = 0.f, s3 = 0.f;
        for (int i = li; i < 512; i += 32) {
            float cv = c3[(p << 9) + i];
            int d1 = (i >> 6) & 7, d2 = (i >> 3) & 7, d3 = i & 7;
            s0 = fmaf(cv, xs[0][d1] * xs[0][d2] * xs[0][d3], s0);
            s1 = fmaf(cv, xs[1][d1] * xs[1][d2] * xs[1][d3], s1);
            s2 = fmaf(cv, xs[2][d1] * xs[2][d2] * xs[2][d3], s2);
            s3 = fmaf(cv, xs[3][d1] * xs[3][d2] * xs[3][d3], s3);
        }
        for (int i = li; i < 64; i += 32) {
            float cv = c2[(p << 6) + i];
            int d1 = (i >> 3) & 7, d2 = i & 7;
            s0 = fmaf(cv, xs[0][d1] * xs[0][d2], s0);
            s1 = fmaf(cv, xs[1][d1] * xs[1][d2], s1);
            s2 = fmaf(cv, xs[2][d1] * xs[2][d2], s2);
            s3 = fmaf(cv, xs[3][d1] * xs[3][d2], s3);
        }
        if (li < 8) {
            float cv = c1[(p << 3) + li];
            s0 = fmaf(cv, xs[0][li], s0);
            s1 = fmaf(cv, xs[1][li], s1);
            s2 = fmaf(cv, xs[2][li], s2);
            s3 = fmaf(cv, xs[3][li], s3);
        }
        redB[p][li][0] = s0; redB[p][li][1] = s1; redB[p][li][2] = s2; redB[p][li][3] = s3;
    }
    __syncthreads();
    if (t < 32) {
        int neu = t >> 3, p = t & 7;
        float tot = bias[p];
        #pragma unroll
        for (int grp = 0; grp < 32; ++grp) tot += redA[t][grp];
        for (int li = 0; li < 32; ++li) tot += redB[p][li][neu];
        out[t] = tot;
    }
}

extern "C" void kernel_launch(void* const* d_in, const int* in_sizes, int n_in,
                              void* d_out, int out_size, void* d_ws, size_t ws_size,
                              hipStream_t stream) {
    const float* X    = (const float*)d_in[0];
    const float* bias = (const float*)d_in[1];
    const float* c1   = (const float*)d_in[2];
    const float* c2   = (const float*)d_in[3];
    const float* c3   = (const float*)d_in[4];
    const float* c4   = (const float*)d_in[5];
    const float* c5   = (const float*)d_in[6];
    const float* c6   = (const float*)d_in[7];
    const float* c7   = (const float*)d_in[8];
    const float* c8   = (const float*)d_in[9];
    float* out = (float*)d_out;
    float* ws  = (float*)d_ws;

    // exactly 4 blocks/CU x 256 CUs resident (LDS-capped): no dispatch tail.
    int blocks = 1024;
    size_t maxb = ws_size / (32 * sizeof(float));
    if ((size_t)blocks > maxb) blocks = (int)maxb;
    if (blocks < 1) blocks = 1;

    poly_big<<<blocks, 256, 0, stream>>>(X, c4, c5, c6, c7, c8, ws);
    poly_final<<<1, 1024, 0, stream>>>(X, bias, c1, c2, c3, ws, blocks, out);
}